// Round 3
// baseline (849.410 us; speedup 1.0000x reference)
//
#include <hip/hip_runtime.h>
#include <stdint.h>

// Experts FFN: E experts, C tokens/expert, D model, F ff
#define E_ 8
#define C_ 4096
#define D_ 1024
#define F_ 4096

typedef __attribute__((ext_vector_type(8))) short bf16x8;
typedef __attribute__((ext_vector_type(4))) float f32x4;
typedef __attribute__((ext_vector_type(8))) unsigned short u16x8;
typedef __attribute__((ext_vector_type(4))) unsigned short u16x4;

__device__ __forceinline__ unsigned short f2bf(float x) {
  union { float f; uint32_t u; } v; v.f = x;
  uint32_t r = v.u + 0x7FFFu + ((v.u >> 16) & 1u);  // RNE
  return (unsigned short)(r >> 16);
}

// JAX gelu (approximate=True)
__device__ __forceinline__ float gelu_f(float x) {
  float x3 = x * x * x;
  float u = 0.7978845608028654f * __builtin_fmaf(0.044715f, x3, x);
  float t = __expf(2.0f * u);
  float th = 1.0f - 2.0f / (t + 1.0f);
  return 0.5f * x * (1.0f + th);
}

// ---------------- elementwise fp32 -> bf16 ----------------
__global__ void convert_bf16_kernel(const float* __restrict__ in,
                                    unsigned short* __restrict__ out, size_t n) {
  size_t i = ((size_t)blockIdx.x * blockDim.x + threadIdx.x) * 8;
  size_t stride = (size_t)gridDim.x * blockDim.x * 8;
  for (; i < n; i += stride) {
    float4 a = *(const float4*)(in + i);
    float4 b = *(const float4*)(in + i + 4);
    u16x8 o;
    o[0] = f2bf(a.x); o[1] = f2bf(a.y); o[2] = f2bf(a.z); o[3] = f2bf(a.w);
    o[4] = f2bf(b.x); o[5] = f2bf(b.y); o[6] = f2bf(b.z); o[7] = f2bf(b.w);
    *(u16x8*)(out + i) = o;
  }
}

// ---------------- tiled transpose: fp32 [K][N] -> bf16 [N][K] ----------------
__global__ void transpose_bf16_kernel(const float* __restrict__ in,
                                      unsigned short* __restrict__ out,
                                      int K, int N) {
  const int ge = blockIdx.z;
  const float* src = in + (size_t)ge * K * N;
  unsigned short* dst = out + (size_t)ge * K * N;
  __shared__ float tile[32][33];
  int t = threadIdx.x;
  int tx = t & 31, ty = t >> 5;  // 32 x 8
  int k0 = blockIdx.x * 32, n0 = blockIdx.y * 32;
#pragma unroll
  for (int p = 0; p < 4; ++p)
    tile[ty + p * 8][tx] = src[(size_t)(k0 + ty + p * 8) * N + n0 + tx];
  __syncthreads();
#pragma unroll
  for (int p = 0; p < 4; ++p)
    dst[(size_t)(n0 + ty + p * 8) * K + k0 + tx] = f2bf(tile[tx][ty + p * 8]);
}

// ---------------- async global->LDS ----------------
typedef const __attribute__((address_space(1))) uint32_t* gas1_ptr;
typedef __attribute__((address_space(3))) uint32_t* las3_ptr;

__device__ __forceinline__ void async16(const void* g, void* l) {
  __builtin_amdgcn_global_load_lds((gas1_ptr)(uintptr_t)g, (las3_ptr)(uintptr_t)l,
                                   16, 0, 0);
}

// ============================================================================
// 256x256 8-phase bf16 GEMM with READ-AHEAD pipeline (T3+T4 counted lgkm/vm):
//   C[M][N] = A[M][K]*B[N][K]^T (+bias); MODE 0: fp32 out; MODE 1: bf16 gelu
// 512 thr = 8 waves (2M x 4N), per-wave 128x64, BK=64, 128 KiB LDS 2-dbuf.
// Quadrant order per buf: (0,0),(0,1),(1,0),(1,1). Reads run ONE PHASE AHEAD:
//   ph1: rd B1@b0(4)  st 1A1(T1)   wait lg(4)  MFMA aE*bZ  (0,0)
//   ph2: rd A1@b0(8)  st 0A0(T+2)  wait lg(8)  MFMA aE*bY  (0,1)
//   ph3: -            st 0B0(T+2)  wait lg(0)  MFMA aO*bZ  (1,0)
//   ph4: rd A0,B0@b1  st 0B1(T+2)  wait lg(12) MFMA aO*bY  (1,1)  <- no stall
//   ph5-8: same with buf roles swapped.
// Uniform vmcnt(8) every sync: last 4 half-tile stages in flight; every
// land-deadline is >= 4 stages old, every restage >= 2 barriers after the
// region's last ds_read (fully re-derived; see analysis in commit).
// Frag regs: aE/aO 32 each + bZ/bY 16 each = 96 VGPR; acc 128 (AGPR).
// ============================================================================

#define SYNC_PRE(VM, LG) do { \
    __builtin_amdgcn_sched_barrier(0); \
    __builtin_amdgcn_s_barrier(); \
    asm volatile("s_waitcnt vmcnt(" #VM ") lgkmcnt(" #LG ")" ::: "memory"); \
    __builtin_amdgcn_sched_barrier(0); \
    __builtin_amdgcn_s_setprio(1); \
  } while (0)

#define SYNC_POST() do { \
    __builtin_amdgcn_s_setprio(0); \
    __builtin_amdgcn_sched_barrier(0); \
    __builtin_amdgcn_s_barrier(); \
    __builtin_amdgcn_sched_barrier(0); \
  } while (0)

template <int MODE>
__global__ __launch_bounds__(512, 2) void gemm256_kernel(
    const unsigned short* __restrict__ A,  // [M][K] bf16
    const unsigned short* __restrict__ B,  // [N][K] bf16
    const float* __restrict__ bias,        // [N]
    void* __restrict__ Cout,
    int K, int N, int numM, int numN,
    size_t aStride, size_t bStride, size_t cStride, int biasStride) {
  __shared__ char lds[131072];
  char* ldsp = (char*)lds;

  const int NT = K >> 6;
  const int NITER = NT >> 1;

  // bijective XCD swizzle (m204)
  int lin = blockIdx.x;
  int nwg = gridDim.x;
  int qq = nwg >> 3, rr8 = nwg & 7;
  int xcd = lin & 7, idx = lin >> 3;
  int wg = (xcd < rr8 ? xcd * (qq + 1) : rr8 * (qq + 1) + (xcd - rr8) * qq) + idx;
  int per = numM * numN;
  int e = wg / per;
  int rem = wg - e * per;
  int tm = rem % numM, tn = rem / numM;

  A += (size_t)e * aStride;
  B += (size_t)e * bStride;
  bias += (size_t)e * biasStride;

  const int rowTile = tm << 8;
  const int colTile = tn << 8;

  const int tid = threadIdx.x;
  const int lane = tid & 63;
  const int w = tid >> 6;
  const int wm = w & 1, wn = w >> 1;
  const int l15 = lane & 15, q = lane >> 4;

  const size_t ldB = (size_t)K * 2;

  // ---- staging: per-lane voffsets (registers) + uniform scalar bases ----
  const int rlo = tid >> 3, kc = tid & 7;
  const int swzsrc = ((kc ^ (rlo & 7)) << 4);
  const int vA = (int)(rlo * (int)ldB) + swzsrc;
  const int bcol = (rlo & 31) + ((rlo >> 5) << 6);
  const int vB = (int)(bcol * (int)ldB) + swzsrc;
  const int dA = tid * 16;
  const int dB = 32768 + (rlo & 31) * 128 + (rlo >> 5) * 8192 + kc * 16;
  const char* Ag = (const char*)A + (size_t)rowTile * ldB;
  const char* Bg = (const char*)B + (size_t)colTile * ldB;
  const size_t r128 = (size_t)128 * ldB;

#define STAGE_A(bb, Ah, kt) do { \
    size_t u = (size_t)((Ah) * 64) * ldB + (size_t)(kt) * 128; \
    async16(Ag + u + vA, ldsp + (bb) * 65536 + (Ah) * 8192 + dA); \
    async16(Ag + u + r128 + vA, \
            ldsp + (bb) * 65536 + (Ah) * 8192 + 16384 + dA); \
  } while (0)

#define STAGE_B(bb, Bh, kt) do { \
    size_t u = (size_t)((Bh) * 32) * ldB + (size_t)(kt) * 128; \
    async16(Bg + u + vB, ldsp + (bb) * 65536 + (Bh) * 4096 + dB); \
    async16(Bg + u + r128 + vB, \
            ldsp + (bb) * 65536 + (Bh) * 4096 + 16384 + dB); \
  } while (0)

  // ---- LDS read base registers (8 ints: buf x ks variants) ----
  const int k0 = (q * 16) ^ ((l15 & 7) << 4);
  const int iA00 = wm * 16384 + l15 * 128 + k0;
  const int iA01 = iA00 ^ 64;
  const int iA10 = iA00 + 65536;
  const int iA11 = iA01 + 65536;
  const int iB00 = 32768 + wn * 8192 + l15 * 128 + k0;
  const int iB01 = iB00 ^ 64;
  const int iB10 = iB00 + 65536;
  const int iB11 = iB01 + 65536;

  bf16x8 aE[4][2], aO[4][2], bZ[2][2], bY[2][2];
  f32x4 acc[8][4];
#pragma unroll
  for (int m = 0; m < 8; ++m)
#pragma unroll
    for (int n = 0; n < 4; ++n) acc[m][n] = {0.f, 0.f, 0.f, 0.f};

#define READ_A(dst, b0, b1, mh) do { \
    _Pragma("unroll") for (int m4 = 0; m4 < 4; ++m4) { \
      dst[m4][0] = *(const bf16x8*)(ldsp + (b0) + (mh) * 8192 + m4 * 2048); \
      dst[m4][1] = *(const bf16x8*)(ldsp + (b1) + (mh) * 8192 + m4 * 2048); \
    } \
  } while (0)

#define READ_B(dst, b0, b1, nh) do { \
    _Pragma("unroll") for (int n2 = 0; n2 < 2; ++n2) { \
      dst[n2][0] = *(const bf16x8*)(ldsp + (b0) + (nh) * 4096 + n2 * 2048); \
      dst[n2][1] = *(const bf16x8*)(ldsp + (b1) + (nh) * 4096 + n2 * 2048); \
    } \
  } while (0)

#define MFMA_Q(mh, nh, AF, BF) do { \
    _Pragma("unroll") for (int m4 = 0; m4 < 4; ++m4) \
    _Pragma("unroll") for (int n2 = 0; n2 < 2; ++n2) \
    _Pragma("unroll") for (int ks = 0; ks < 2; ++ks) \
      acc[(mh) * 4 + m4][(nh) * 2 + n2] = \
          __builtin_amdgcn_mfma_f32_16x16x32_bf16( \
              BF[n2][ks], AF[m4][ks], acc[(mh) * 4 + m4][(nh) * 2 + n2], 0, 0, 0); \
  } while (0)

  // ---- prologue: stage 0A0,0B0,0B1,0A1 (tile0), 1A0,1B0,1B1 (tile1) ----
  STAGE_A(0, 0, 0); STAGE_B(0, 0, 0); STAGE_B(0, 1, 0); STAGE_A(0, 1, 0);
  STAGE_A(1, 0, 1); STAGE_B(1, 0, 1); STAGE_B(1, 1, 1);
  asm volatile("s_waitcnt vmcnt(6)" ::: "memory");  // buf0 landed
  __builtin_amdgcn_sched_barrier(0);
  __builtin_amdgcn_s_barrier();
  __builtin_amdgcn_sched_barrier(0);
  READ_A(aE, iA00, iA01, 0);   // A0@buf0
  READ_B(bZ, iB00, iB01, 0);   // B0@buf0

  for (int j = 0; j < NITER; ++j) {
    int t1 = 2 * j + 1;
    int t2 = 2 * j + 2; if (t2 > NT - 1) t2 = NT - 1;
    int t3 = 2 * j + 3; if (t3 > NT - 1) t3 = NT - 1;

    // ph1: rd B1@b0 -> bY; st 1A1(t1)
    READ_B(bY, iB00, iB01, 1);
    STAGE_A(1, 1, t1);
    SYNC_PRE(8, 4); MFMA_Q(0, 0, aE, bZ); SYNC_POST();
    // ph2: rd A1@b0 -> aO; st 0A0(t2)
    READ_A(aO, iA00, iA01, 1);
    STAGE_A(0, 0, t2);
    SYNC_PRE(8, 8); MFMA_Q(0, 1, aE, bY); SYNC_POST();
    // ph3: st 0B0(t2)
    STAGE_B(0, 0, t2);
    SYNC_PRE(8, 0); MFMA_Q(1, 0, aO, bZ); SYNC_POST();
    // ph4: rd A0,B0@b1 -> aE,bZ; st 0B1(t2); no lgkm stall
    READ_A(aE, iA10, iA11, 0);
    READ_B(bZ, iB10, iB11, 0);
    STAGE_B(0, 1, t2);
    SYNC_PRE(8, 12); MFMA_Q(1, 1, aO, bY); SYNC_POST();
    // ph5: rd B1@b1 -> bY; st 0A1(t2)
    READ_B(bY, iB10, iB11, 1);
    STAGE_A(0, 1, t2);
    SYNC_PRE(8, 4); MFMA_Q(0, 0, aE, bZ); SYNC_POST();
    // ph6: rd A1@b1 -> aO; st 1A0(t3)
    READ_A(aO, iA10, iA11, 1);
    STAGE_A(1, 0, t3);
    SYNC_PRE(8, 8); MFMA_Q(0, 1, aE, bY); SYNC_POST();
    // ph7: st 1B0(t3)
    STAGE_B(1, 0, t3);
    SYNC_PRE(8, 0); MFMA_Q(1, 0, aO, bZ); SYNC_POST();
    // ph8: rd A0,B0@b0 (t2 content) -> aE,bZ; st 1B1(t3); no lgkm stall
    READ_A(aE, iA00, iA01, 0);
    READ_B(bZ, iB00, iB01, 0);
    STAGE_B(1, 1, t3);
    SYNC_PRE(8, 12); MFMA_Q(1, 1, aO, bY); SYNC_POST();
  }
  asm volatile("s_waitcnt vmcnt(0) lgkmcnt(0)" ::: "memory");  // drain
  __builtin_amdgcn_sched_barrier(0);

  // ---- epilogue: swapped layout => lane l15 = row, q*4+j = col ----
#pragma unroll
  for (int mf = 0; mf < 8; ++mf) {
    int row = rowTile + wm * 128 + mf * 16 + l15;
#pragma unroll
    for (int nf = 0; nf < 4; ++nf) {
      int col = colTile + wn * 64 + nf * 16 + q * 4;
      float4 bv = *(const float4*)(bias + col);
      f32x4 v = acc[mf][nf];
      if constexpr (MODE == 1) {
        u16x4 o;
        o[0] = f2bf(gelu_f(v[0] + bv.x));
        o[1] = f2bf(gelu_f(v[1] + bv.y));
        o[2] = f2bf(gelu_f(v[2] + bv.z));
        o[3] = f2bf(gelu_f(v[3] + bv.w));
        *(u16x4*)((unsigned short*)Cout + (size_t)e * cStride +
                  (size_t)row * N + col) = o;
      } else {
        float4 o;
        o.x = v[0] + bv.x; o.y = v[1] + bv.y;
        o.z = v[2] + bv.z; o.w = v[3] + bv.w;
        *(float4*)((float*)Cout + (size_t)e * cStride + (size_t)row * N + col) = o;
      }
    }
  }
}

extern "C" void kernel_launch(void* const* d_in, const int* in_sizes, int n_in,
                              void* d_out, int out_size, void* d_ws, size_t ws_size,
                              hipStream_t stream) {
  const float* X = (const float*)d_in[0];   // [1][E*C][D]
  const float* W1 = (const float*)d_in[1];  // [E][D][F]
  const float* b1 = (const float*)d_in[2];  // [E][F]
  const float* W2 = (const float*)d_in[3];  // [E][F][D]
  const float* b2 = (const float*)d_in[4];  // [E][D]
  float* Y = (float*)d_out;                 // [1][E*C][D]

  const size_t szX = (size_t)C_ * D_ * 2;
  const size_t szW1 = (size_t)F_ * D_ * 2;
  const size_t szW2 = (size_t)D_ * F_ * 2;
  const size_t szH = (size_t)C_ * F_ * 2;
  const size_t fixed = szX + szW1 + szW2;

  int g = 0;
  {
    const int cands[4] = {8, 4, 2, 1};
    for (int i = 0; i < 4; ++i)
      if ((fixed + szH) * (size_t)cands[i] <= ws_size) { g = cands[i]; break; }
  }
  int RC = C_;
  if (g == 0) {  // tiny-ws fallback: chunk rows (256-granular for BM=256)
    g = 1;
    size_t avail = ws_size > fixed ? ws_size - fixed : 0;
    RC = (int)(avail / ((size_t)F_ * 2));
    RC = (RC / 256) * 256;
    if (RC < 256) RC = 256;
    if (RC > C_) RC = C_;
  }

  unsigned short* XB = (unsigned short*)d_ws;              // [g][C][D]
  unsigned short* W1T = XB + (size_t)g * C_ * D_;          // [g][F][D]
  unsigned short* W2T = W1T + (size_t)g * F_ * D_;         // [g][D][F]
  unsigned short* H = W2T + (size_t)g * D_ * F_;           // [g][RC][F]

  const int numN1 = F_ / 256;  // 16
  const int numN2 = D_ / 256;  // 4

  for (int e0 = 0; e0 < E_; e0 += g) {
    {
      size_t n = (size_t)g * C_ * D_;
      size_t nb = (n / 8 + 255) / 256;
      if (nb > 2048) nb = 2048;
      convert_bf16_kernel<<<dim3((unsigned)nb), 256, 0, stream>>>(
          X + (size_t)e0 * C_ * D_, XB, n);
    }
    transpose_bf16_kernel<<<dim3(D_ / 32, F_ / 32, g), 256, 0, stream>>>(
        W1 + (size_t)e0 * D_ * F_, W1T, D_, F_);
    transpose_bf16_kernel<<<dim3(F_ / 32, D_ / 32, g), 256, 0, stream>>>(
        W2 + (size_t)e0 * F_ * D_, W2T, F_, D_);

    for (int r0 = 0; r0 < C_; r0 += RC) {
      int numM = RC / 256;
      // GEMM1: H = gelu(XB @ W1T^T + b1), [RC x F], K = D
      gemm256_kernel<1><<<dim3((unsigned)(numM * numN1 * g)), 512, 0, stream>>>(
          XB + (size_t)r0 * D_, W1T, b1 + (size_t)e0 * F_, (void*)H,
          D_, F_, numM, numN1,
          (size_t)C_ * D_, (size_t)F_ * D_, (size_t)RC * F_, F_);
      // GEMM2: Y = H @ W2T^T + b2, [RC x D], K = F
      gemm256_kernel<0><<<dim3((unsigned)(numM * numN2 * g)), 512, 0, stream>>>(
          H, W2T, b2 + (size_t)e0 * D_,
          (void*)(Y + (size_t)e0 * C_ * D_ + (size_t)r0 * D_),
          F_, D_, numM, numN2,
          (size_t)RC * F_, (size_t)D_ * F_, (size_t)C_ * D_, D_);
    }
  }
}

// Round 4
// 751.948 us; speedup vs baseline: 1.1296x; 1.1296x over previous
//
#include <hip/hip_runtime.h>
#include <stdint.h>

// Experts FFN: E experts, C tokens/expert, D model, F ff
#define E_ 8
#define C_ 4096
#define D_ 1024
#define F_ 4096

typedef __attribute__((ext_vector_type(8))) short bf16x8;
typedef __attribute__((ext_vector_type(4))) float f32x4;
typedef __attribute__((ext_vector_type(8))) unsigned short u16x8;
typedef __attribute__((ext_vector_type(4))) unsigned short u16x4;

__device__ __forceinline__ unsigned short f2bf(float x) {
  union { float f; uint32_t u; } v; v.f = x;
  uint32_t r = v.u + 0x7FFFu + ((v.u >> 16) & 1u);  // RNE
  return (unsigned short)(r >> 16);
}

// JAX gelu (approximate=True)
__device__ __forceinline__ float gelu_f(float x) {
  float x3 = x * x * x;
  float u = 0.7978845608028654f * __builtin_fmaf(0.044715f, x3, x);
  float t = __expf(2.0f * u);
  float th = 1.0f - 2.0f / (t + 1.0f);
  return 0.5f * x * (1.0f + th);
}

// ---------------- elementwise fp32 -> bf16 ----------------
__global__ void convert_bf16_kernel(const float* __restrict__ in,
                                    unsigned short* __restrict__ out, size_t n) {
  size_t i = ((size_t)blockIdx.x * blockDim.x + threadIdx.x) * 8;
  size_t stride = (size_t)gridDim.x * blockDim.x * 8;
  for (; i < n; i += stride) {
    float4 a = *(const float4*)(in + i);
    float4 b = *(const float4*)(in + i + 4);
    u16x8 o;
    o[0] = f2bf(a.x); o[1] = f2bf(a.y); o[2] = f2bf(a.z); o[3] = f2bf(a.w);
    o[4] = f2bf(b.x); o[5] = f2bf(b.y); o[6] = f2bf(b.z); o[7] = f2bf(b.w);
    *(u16x8*)(out + i) = o;
  }
}

// ---------------- tiled transpose: fp32 [K][N] -> bf16 [N][K] ----------------
__global__ void transpose_bf16_kernel(const float* __restrict__ in,
                                      unsigned short* __restrict__ out,
                                      int K, int N) {
  const int ge = blockIdx.z;
  const float* src = in + (size_t)ge * K * N;
  unsigned short* dst = out + (size_t)ge * K * N;
  __shared__ float tile[32][33];
  int t = threadIdx.x;
  int tx = t & 31, ty = t >> 5;  // 32 x 8
  int k0 = blockIdx.x * 32, n0 = blockIdx.y * 32;
#pragma unroll
  for (int p = 0; p < 4; ++p)
    tile[ty + p * 8][tx] = src[(size_t)(k0 + ty + p * 8) * N + n0 + tx];
  __syncthreads();
#pragma unroll
  for (int p = 0; p < 4; ++p)
    dst[(size_t)(n0 + ty + p * 8) * K + k0 + tx] = f2bf(tile[tx][ty + p * 8]);
}

// ---------------- async global->LDS ----------------
typedef const __attribute__((address_space(1))) uint32_t* gas1_ptr;
typedef __attribute__((address_space(3))) uint32_t* las3_ptr;

__device__ __forceinline__ void async16(const void* g, void* l) {
  __builtin_amdgcn_global_load_lds((gas1_ptr)(uintptr_t)g, (las3_ptr)(uintptr_t)l,
                                   16, 0, 0);
}

// ============================================================================
// 256x256 8-phase bf16 GEMM, CLUSTER-OVERLAPPED pipeline:
//   C[M][N] = A[M][K]*B[N][K]^T (+bias); MODE 0: fp32 out; MODE 1: bf16 gelu
// 512 thr = 8 waves (2M x 4N), per-wave 128x64, BK=64, 128 KiB LDS 2-dbuf.
// Per phase: PRE{vmcnt(n); barrier; lgkmcnt(0)} -> [STAGE + next-phase
// ds_reads + 16 MFMA all in ONE inter-barrier window] -> POST{barrier}.
// The ds_read burst and LDS-DMA execute WHILE the matrix pipe crunches the
// cluster; by the next lgkmcnt(0) they are done (R2's serialization killer).
// Quadrants: ph1 (0,0) aE*bZ, ph2 (0,1) aE*bY, ph3 (1,0) aO*bZ, ph4 (1,1)
// aO*bY (then same in buf1). Reads: ph1: bY; ph2: aO; ph4: aE',bZ'.
// Stages (tile t+1 into other buf): ph1: A0+B0, ph3: B1, ph4: A1.
// vm-waits {ph1:2, ph2:4, ph3:4, ph4:2} BEFORE the barrier: ledger-exact —
// each forced retire is precisely the region the upcoming cluster reads,
// landed 3 phases after issue. Region restage >= 5 phases after last read;
// frag-reg overwrites >= 1 phase after last MFMA consumer.
// ============================================================================

#define PRE(VM) do { \
    __builtin_amdgcn_sched_barrier(0); \
    asm volatile("s_waitcnt vmcnt(" #VM ")" ::: "memory"); \
    __builtin_amdgcn_s_barrier(); \
    asm volatile("s_waitcnt lgkmcnt(0)" ::: "memory"); \
    __builtin_amdgcn_sched_barrier(0); \
    __builtin_amdgcn_s_setprio(1); \
  } while (0)

#define POST() do { \
    __builtin_amdgcn_s_setprio(0); \
    __builtin_amdgcn_sched_barrier(0); \
    __builtin_amdgcn_s_barrier(); \
    __builtin_amdgcn_sched_barrier(0); \
  } while (0)

template <int MODE>
__global__ __launch_bounds__(512, 2) void gemm256_kernel(
    const unsigned short* __restrict__ A,  // [M][K] bf16
    const unsigned short* __restrict__ B,  // [N][K] bf16
    const float* __restrict__ bias,        // [N]
    void* __restrict__ Cout,
    int K, int N, int numM, int numN,
    size_t aStride, size_t bStride, size_t cStride, int biasStride) {
  __shared__ char lds[131072];
  char* ldsp = (char*)lds;

  const int NT = K >> 6;
  const int NITER = NT >> 1;

  // bijective XCD swizzle (m204)
  int lin = blockIdx.x;
  int nwg = gridDim.x;
  int qq = nwg >> 3, rr8 = nwg & 7;
  int xcd = lin & 7, idx = lin >> 3;
  int wg = (xcd < rr8 ? xcd * (qq + 1) : rr8 * (qq + 1) + (xcd - rr8) * qq) + idx;
  int per = numM * numN;
  int e = wg / per;
  int rem = wg - e * per;
  int tm = rem % numM, tn = rem / numM;

  A += (size_t)e * aStride;
  B += (size_t)e * bStride;
  bias += (size_t)e * biasStride;

  const int rowTile = tm << 8;
  const int colTile = tn << 8;

  const int tid = threadIdx.x;
  const int lane = tid & 63;
  const int w = tid >> 6;
  const int wm = w & 1, wn = w >> 1;
  const int l15 = lane & 15, q = lane >> 4;

  const size_t ldB = (size_t)K * 2;

  // ---- staging: per-lane voffsets + uniform scalar bases ----
  const int rlo = tid >> 3, kc = tid & 7;
  const int swzsrc = ((kc ^ (rlo & 7)) << 4);
  const int vA = (int)(rlo * (int)ldB) + swzsrc;
  const int bcol = (rlo & 31) + ((rlo >> 5) << 6);
  const int vB = (int)(bcol * (int)ldB) + swzsrc;
  const int dA = tid * 16;
  const int dB = 32768 + (rlo & 31) * 128 + (rlo >> 5) * 8192 + kc * 16;
  const char* Ag = (const char*)A + (size_t)rowTile * ldB;
  const char* Bg = (const char*)B + (size_t)colTile * ldB;
  const size_t r128 = (size_t)128 * ldB;

#define STAGE_A(bb, Ah, kt) do { \
    size_t u = (size_t)((Ah) * 64) * ldB + (size_t)(kt) * 128; \
    async16(Ag + u + vA, ldsp + (bb) * 65536 + (Ah) * 8192 + dA); \
    async16(Ag + u + r128 + vA, \
            ldsp + (bb) * 65536 + (Ah) * 8192 + 16384 + dA); \
  } while (0)

#define STAGE_B(bb, Bh, kt) do { \
    size_t u = (size_t)((Bh) * 32) * ldB + (size_t)(kt) * 128; \
    async16(Bg + u + vB, ldsp + (bb) * 65536 + (Bh) * 4096 + dB); \
    async16(Bg + u + r128 + vB, \
            ldsp + (bb) * 65536 + (Bh) * 4096 + 16384 + dB); \
  } while (0)

  // ---- LDS read base offsets (buf x ks variants) ----
  const int k0 = (q * 16) ^ ((l15 & 7) << 4);
  const int iA00 = wm * 16384 + l15 * 128 + k0;
  const int iA01 = iA00 ^ 64;
  const int iA10 = iA00 + 65536;
  const int iA11 = iA01 + 65536;
  const int iB00 = 32768 + wn * 8192 + l15 * 128 + k0;
  const int iB01 = iB00 ^ 64;
  const int iB10 = iB00 + 65536;
  const int iB11 = iB01 + 65536;

  bf16x8 aE[4][2], aO[4][2], bZ[2][2], bY[2][2];
  f32x4 acc[8][4];
#pragma unroll
  for (int m = 0; m < 8; ++m)
#pragma unroll
    for (int n = 0; n < 4; ++n) acc[m][n] = {0.f, 0.f, 0.f, 0.f};

#define READ_A(dst, b0, b1, mh) do { \
    _Pragma("unroll") for (int m4 = 0; m4 < 4; ++m4) { \
      dst[m4][0] = *(const bf16x8*)(ldsp + (b0) + (mh) * 8192 + m4 * 2048); \
      dst[m4][1] = *(const bf16x8*)(ldsp + (b1) + (mh) * 8192 + m4 * 2048); \
    } \
  } while (0)

#define READ_B(dst, b0, b1, nh) do { \
    _Pragma("unroll") for (int n2 = 0; n2 < 2; ++n2) { \
      dst[n2][0] = *(const bf16x8*)(ldsp + (b0) + (nh) * 4096 + n2 * 2048); \
      dst[n2][1] = *(const bf16x8*)(ldsp + (b1) + (nh) * 4096 + n2 * 2048); \
    } \
  } while (0)

#define MFMA_Q(mh, nh, AF, BF) do { \
    _Pragma("unroll") for (int m4 = 0; m4 < 4; ++m4) \
    _Pragma("unroll") for (int n2 = 0; n2 < 2; ++n2) \
    _Pragma("unroll") for (int ks = 0; ks < 2; ++ks) \
      acc[(mh) * 4 + m4][(nh) * 2 + n2] = \
          __builtin_amdgcn_mfma_f32_16x16x32_bf16( \
              BF[n2][ks], AF[m4][ks], acc[(mh) * 4 + m4][(nh) * 2 + n2], 0, 0, 0); \
  } while (0)

  // ---- prologue: tile0 -> buf0 only; tile1 staged inside loop ----
  STAGE_A(0, 0, 0); STAGE_B(0, 0, 0); STAGE_B(0, 1, 0); STAGE_A(0, 1, 0);
  asm volatile("s_waitcnt vmcnt(0)" ::: "memory");
  __builtin_amdgcn_sched_barrier(0);
  __builtin_amdgcn_s_barrier();
  __builtin_amdgcn_sched_barrier(0);
  READ_A(aE, iA00, iA01, 0);   // A0@buf0
  READ_B(bZ, iB00, iB01, 0);   // B0@buf0

  for (int j = 0; j < NITER; ++j) {
    int t1 = 2 * j + 1;
    int t2 = 2 * j + 2; if (t2 > NT - 1) t2 = NT - 1;

    // ph1 (tile 2j, buf0) quad(0,0): stage A0,B0(t1)->b1; read bY<-B1@b0
    PRE(2);
    STAGE_A(1, 0, t1); STAGE_B(1, 0, t1);
    READ_B(bY, iB00, iB01, 1);
    MFMA_Q(0, 0, aE, bZ);
    POST();
    // ph2 quad(0,1): read aO<-A1@b0
    PRE(4);
    READ_A(aO, iA00, iA01, 1);
    MFMA_Q(0, 1, aE, bY);
    POST();
    // ph3 quad(1,0): stage B1(t1)->b1
    PRE(4);
    STAGE_B(1, 1, t1);
    MFMA_Q(1, 0, aO, bZ);
    POST();
    // ph4 quad(1,1): stage A1(t1)->b1; read aE<-A0@b1, bZ<-B0@b1
    PRE(2);
    STAGE_A(1, 1, t1);
    READ_A(aE, iA10, iA11, 0);
    READ_B(bZ, iB10, iB11, 0);
    MFMA_Q(1, 1, aO, bY);
    POST();
    // ph5 (tile 2j+1, buf1) quad(0,0): stage A0,B0(t2)->b0; read bY<-B1@b1
    PRE(2);
    STAGE_A(0, 0, t2); STAGE_B(0, 0, t2);
    READ_B(bY, iB10, iB11, 1);
    MFMA_Q(0, 0, aE, bZ);
    POST();
    // ph6 quad(0,1): read aO<-A1@b1
    PRE(4);
    READ_A(aO, iA10, iA11, 1);
    MFMA_Q(0, 1, aE, bY);
    POST();
    // ph7 quad(1,0): stage B1(t2)->b0
    PRE(4);
    STAGE_B(0, 1, t2);
    MFMA_Q(1, 0, aO, bZ);
    POST();
    // ph8 quad(1,1): stage A1(t2)->b0; read aE<-A0@b0, bZ<-B0@b0
    PRE(2);
    STAGE_A(0, 1, t2);
    READ_A(aE, iA00, iA01, 0);
    READ_B(bZ, iB00, iB01, 0);
    MFMA_Q(1, 1, aO, bY);
    POST();
  }
  asm volatile("s_waitcnt vmcnt(0) lgkmcnt(0)" ::: "memory");
  __builtin_amdgcn_sched_barrier(0);

  // ---- epilogue: swapped layout => lane l15 = row, q*4+j = col ----
#pragma unroll
  for (int mf = 0; mf < 8; ++mf) {
    int row = rowTile + wm * 128 + mf * 16 + l15;
#pragma unroll
    for (int nf = 0; nf < 4; ++nf) {
      int col = colTile + wn * 64 + nf * 16 + q * 4;
      float4 bv = *(const float4*)(bias + col);
      f32x4 v = acc[mf][nf];
      if constexpr (MODE == 1) {
        u16x4 o;
        o[0] = f2bf(gelu_f(v[0] + bv.x));
        o[1] = f2bf(gelu_f(v[1] + bv.y));
        o[2] = f2bf(gelu_f(v[2] + bv.z));
        o[3] = f2bf(gelu_f(v[3] + bv.w));
        *(u16x4*)((unsigned short*)Cout + (size_t)e * cStride +
                  (size_t)row * N + col) = o;
      } else {
        float4 o;
        o.x = v[0] + bv.x; o.y = v[1] + bv.y;
        o.z = v[2] + bv.z; o.w = v[3] + bv.w;
        *(float4*)((float*)Cout + (size_t)e * cStride + (size_t)row * N + col) = o;
      }
    }
  }
}

extern "C" void kernel_launch(void* const* d_in, const int* in_sizes, int n_in,
                              void* d_out, int out_size, void* d_ws, size_t ws_size,
                              hipStream_t stream) {
  const float* X = (const float*)d_in[0];   // [1][E*C][D]
  const float* W1 = (const float*)d_in[1];  // [E][D][F]
  const float* b1 = (const float*)d_in[2];  // [E][F]
  const float* W2 = (const float*)d_in[3];  // [E][F][D]
  const float* b2 = (const float*)d_in[4];  // [E][D]
  float* Y = (float*)d_out;                 // [1][E*C][D]

  const size_t szX = (size_t)C_ * D_ * 2;
  const size_t szW1 = (size_t)F_ * D_ * 2;
  const size_t szW2 = (size_t)D_ * F_ * 2;
  const size_t szH = (size_t)C_ * F_ * 2;
  const size_t fixed = szX + szW1 + szW2;

  int g = 0;
  {
    const int cands[4] = {8, 4, 2, 1};
    for (int i = 0; i < 4; ++i)
      if ((fixed + szH) * (size_t)cands[i] <= ws_size) { g = cands[i]; break; }
  }
  int RC = C_;
  if (g == 0) {  // tiny-ws fallback: chunk rows (256-granular for BM=256)
    g = 1;
    size_t avail = ws_size > fixed ? ws_size - fixed : 0;
    RC = (int)(avail / ((size_t)F_ * 2));
    RC = (RC / 256) * 256;
    if (RC < 256) RC = 256;
    if (RC > C_) RC = C_;
  }

  unsigned short* XB = (unsigned short*)d_ws;              // [g][C][D]
  unsigned short* W1T = XB + (size_t)g * C_ * D_;          // [g][F][D]
  unsigned short* W2T = W1T + (size_t)g * F_ * D_;         // [g][D][F]
  unsigned short* H = W2T + (size_t)g * D_ * F_;           // [g][RC][F]

  const int numN1 = F_ / 256;  // 16
  const int numN2 = D_ / 256;  // 4

  for (int e0 = 0; e0 < E_; e0 += g) {
    {
      size_t n = (size_t)g * C_ * D_;
      size_t nb = (n / 8 + 255) / 256;
      if (nb > 2048) nb = 2048;
      convert_bf16_kernel<<<dim3((unsigned)nb), 256, 0, stream>>>(
          X + (size_t)e0 * C_ * D_, XB, n);
    }
    transpose_bf16_kernel<<<dim3(D_ / 32, F_ / 32, g), 256, 0, stream>>>(
        W1 + (size_t)e0 * D_ * F_, W1T, D_, F_);
    transpose_bf16_kernel<<<dim3(F_ / 32, D_ / 32, g), 256, 0, stream>>>(
        W2 + (size_t)e0 * F_ * D_, W2T, F_, D_);

    for (int r0 = 0; r0 < C_; r0 += RC) {
      int numM = RC / 256;
      // GEMM1: H = gelu(XB @ W1T^T + b1), [RC x F], K = D
      gemm256_kernel<1><<<dim3((unsigned)(numM * numN1 * g)), 512, 0, stream>>>(
          XB + (size_t)r0 * D_, W1T, b1 + (size_t)e0 * F_, (void*)H,
          D_, F_, numM, numN1,
          (size_t)C_ * D_, (size_t)F_ * D_, (size_t)RC * F_, F_);
      // GEMM2: Y = H @ W2T^T + b2, [RC x D], K = F
      gemm256_kernel<0><<<dim3((unsigned)(numM * numN2 * g)), 512, 0, stream>>>(
          H, W2T, b2 + (size_t)e0 * D_,
          (void*)(Y + (size_t)e0 * C_ * D_ + (size_t)r0 * D_),
          F_, D_, numM, numN2,
          (size_t)RC * F_, (size_t)D_ * F_, (size_t)C_ * D_, D_);
    }
  }
}